// Round 8
// baseline (203.917 us; speedup 1.0000x reference)
//
#include <hip/hip_runtime.h>

typedef unsigned short u16;
typedef unsigned int u32;
typedef short bf16x8 __attribute__((ext_vector_type(8)));
typedef float f32x4 __attribute__((ext_vector_type(4)));
typedef float f32x16 __attribute__((ext_vector_type(16)));
typedef u32 u32x4 __attribute__((ext_vector_type(4)));

#define S_LEN 4096
#define DM 1024
#define NH 16
#define DH 64
#define CE 0.18033688f   // (1/sqrt(64)) * log2(e)  -- folded into Q projection
#define THR 8.0f

typedef const __attribute__((address_space(1))) u32 gu32;
typedef __attribute__((address_space(3))) u32 lu32;

__device__ __forceinline__ u16 f2bf(float f) {
  u32 u = __builtin_bit_cast(u32, f);
  u += 0x7fff + ((u >> 16) & 1);
  return (u16)(u >> 16);
}

__device__ __forceinline__ f32x16 zero16() {
  f32x16 z;
#pragma unroll
  for (int i = 0; i < 16; ++i) z[i] = 0.f;
  return z;
}

__device__ __forceinline__ u32 cvt_pk_bf16(float lo, float hi) {
  u32 r;
  asm("v_cvt_pk_bf16_f32 %0, %1, %2" : "=v"(r) : "v"(lo), "v"(hi));
  return r;
}

// v_permlane32_swap_b32 a, b:
//   new_a[32..63] = old_b[0..31]; new_b[0..31] = old_a[32..63]; rest kept.
// SAFETY: operands must be DISTINCT SSA values (same-value operands can be
// CSE'd into one VGPR -> corrupt swap; this caused r4's NaN via swap_fmax).
__device__ __forceinline__ void pl_swap(u32& a, u32& b) {
  asm("v_permlane32_swap_b32 %0, %1" : "+v"(a), "+v"(b));
}

// ---------------- fp32 -> bf16 conversion ----------------
__global__ void cvt_bf16(const float* __restrict__ in, u16* __restrict__ out, int n4) {
  int i = blockIdx.x * blockDim.x + threadIdx.x;
  if (i < n4) {
    float4 v = ((const float4*)in)[i];
    ushort4 o;
    o.x = f2bf(v.x); o.y = f2bf(v.y); o.z = f2bf(v.z); o.w = f2bf(v.w);
    ((ushort4*)out)[i] = o;
  }
}

// fused 4-weight convert: blockIdx.y selects which weight matrix
__global__ void cvt_bf16_w4(const float* __restrict__ a, const float* __restrict__ b,
                            const float* __restrict__ c, const float* __restrict__ d,
                            u16* __restrict__ oa, u16* __restrict__ ob2,
                            u16* __restrict__ oc, u16* __restrict__ od, int n4) {
  const int w = blockIdx.y;
  const float* src = (w == 0) ? a : (w == 1) ? b : (w == 2) ? c : d;
  u16* dst = (w == 0) ? oa : (w == 1) ? ob2 : (w == 2) ? oc : od;
  int i = blockIdx.x * blockDim.x + threadIdx.x;
  if (i < n4) {
    float4 v = ((const float4*)src)[i];
    ushort4 o;
    o.x = f2bf(v.x); o.y = f2bf(v.y); o.z = f2bf(v.z); o.w = f2bf(v.w);
    ((ushort4*)dst)[i] = o;
  }
}

// ---------------- fused QKV projection GEMM ----------------
// z=0: Q = (x Wq^T + bq) * CE   -> row-major bf16
// z=1: K = x Wk^T + bk          -> row-major bf16
// z=2: V = x Wv^T + bv          -> TRANSPOSED bf16 [DM][S]
__global__ __launch_bounds__(256) void gemm_qkv(const u16* __restrict__ A,
                                                const u16* __restrict__ Wq_, const u16* __restrict__ Wk_, const u16* __restrict__ Wv_,
                                                const float* __restrict__ bq_, const float* __restrict__ bk_, const float* __restrict__ bv_,
                                                u16* __restrict__ Qo, u16* __restrict__ Ko, u16* __restrict__ Vo) {
  __shared__ __align__(16) u16 As[128 * 32];
  __shared__ __align__(16) u16 Bs[128 * 32];
  const int z = blockIdx.z;
  const u16* Bt = (z == 0) ? Wq_ : (z == 1) ? Wk_ : Wv_;
  const float* bias = (z == 0) ? bq_ : (z == 1) ? bk_ : bv_;

  const int tid = threadIdx.x;
  const int lane = tid & 63;
  const int wid = tid >> 6;
  const int wm = wid >> 1, wn = wid & 1;
  const int bm = blockIdx.x * 128, bn = blockIdx.y * 128;
  const int lr = lane & 15, lg = lane >> 4;

  f32x4 acc[4][4];
#pragma unroll
  for (int i = 0; i < 4; ++i)
#pragma unroll
    for (int j = 0; j < 4; ++j) acc[i][j] = f32x4{0.f, 0.f, 0.f, 0.f};

  const int r0 = tid >> 2;
  const int c0 = (tid & 3) * 8;
  const u16* ga0 = A + (size_t)(bm + r0) * DM + c0;
  const u16* gb0 = Bt + (size_t)(bn + r0) * DM + c0;

  for (int kt = 0; kt < DM; kt += 32) {
    __builtin_amdgcn_global_load_lds((gu32*)(ga0 + kt),            (lu32*)(As + tid * 8),        16, 0, 0);
    __builtin_amdgcn_global_load_lds((gu32*)(ga0 + 64 * DM + kt),  (lu32*)(As + 2048 + tid * 8), 16, 0, 0);
    __builtin_amdgcn_global_load_lds((gu32*)(gb0 + kt),            (lu32*)(Bs + tid * 8),        16, 0, 0);
    __builtin_amdgcn_global_load_lds((gu32*)(gb0 + 64 * DM + kt),  (lu32*)(Bs + 2048 + tid * 8), 16, 0, 0);
    __syncthreads();
    bf16x8 af[4], bfr[4];
#pragma unroll
    for (int i = 0; i < 4; ++i) af[i] = *(const bf16x8*)&As[(wm * 64 + i * 16 + lr) * 32 + lg * 8];
#pragma unroll
    for (int j = 0; j < 4; ++j) bfr[j] = *(const bf16x8*)&Bs[(wn * 64 + j * 16 + lr) * 32 + lg * 8];
#pragma unroll
    for (int i = 0; i < 4; ++i)
#pragma unroll
      for (int j = 0; j < 4; ++j)
        acc[i][j] = __builtin_amdgcn_mfma_f32_16x16x32_bf16(af[i], bfr[j], acc[i][j], 0, 0, 0);
    __syncthreads();
  }

#pragma unroll
  for (int i = 0; i < 4; ++i) {
    const int row = bm + wm * 64 + i * 16 + lg * 4;
#pragma unroll
    for (int j = 0; j < 4; ++j) {
      const int col = bn + wn * 64 + j * 16 + lr;
      const float b = bias[col];
#pragma unroll
      for (int r = 0; r < 4; ++r) {
        const float v = acc[i][j][r] + b;
        if (z == 0)      Qo[(size_t)(row + r) * DM + col] = f2bf(v * CE);
        else if (z == 1) Ko[(size_t)(row + r) * DM + col] = f2bf(v);
        else             Vo[(size_t)col * S_LEN + (row + r)] = f2bf(v);
      }
    }
  }
}

// ---------------- output GEMM: C[M,N] = A[M,K] * Bt[N,K]^T + bias (fp32 out) ----------------
__global__ __launch_bounds__(256) void gemm_out(const u16* __restrict__ A,
                                                const u16* __restrict__ Bt,
                                                const float* __restrict__ bias,
                                                float* __restrict__ Cp) {
  __shared__ __align__(16) u16 As[128 * 32];
  __shared__ __align__(16) u16 Bs[128 * 32];
  const int tid = threadIdx.x;
  const int lane = tid & 63;
  const int wid = tid >> 6;
  const int wm = wid >> 1, wn = wid & 1;
  const int bm = blockIdx.x * 128, bn = blockIdx.y * 128;
  const int lr = lane & 15, lg = lane >> 4;

  f32x4 acc[4][4];
#pragma unroll
  for (int i = 0; i < 4; ++i)
#pragma unroll
    for (int j = 0; j < 4; ++j) acc[i][j] = f32x4{0.f, 0.f, 0.f, 0.f};

  const int r0 = tid >> 2;
  const int c0 = (tid & 3) * 8;
  const u16* ga0 = A + (size_t)(bm + r0) * DM + c0;
  const u16* gb0 = Bt + (size_t)(bn + r0) * DM + c0;

  for (int kt = 0; kt < DM; kt += 32) {
    __builtin_amdgcn_global_load_lds((gu32*)(ga0 + kt),            (lu32*)(As + tid * 8),        16, 0, 0);
    __builtin_amdgcn_global_load_lds((gu32*)(ga0 + 64 * DM + kt),  (lu32*)(As + 2048 + tid * 8), 16, 0, 0);
    __builtin_amdgcn_global_load_lds((gu32*)(gb0 + kt),            (lu32*)(Bs + tid * 8),        16, 0, 0);
    __builtin_amdgcn_global_load_lds((gu32*)(gb0 + 64 * DM + kt),  (lu32*)(Bs + 2048 + tid * 8), 16, 0, 0);
    __syncthreads();
    bf16x8 af[4], bfr[4];
#pragma unroll
    for (int i = 0; i < 4; ++i) af[i] = *(const bf16x8*)&As[(wm * 64 + i * 16 + lr) * 32 + lg * 8];
#pragma unroll
    for (int j = 0; j < 4; ++j) bfr[j] = *(const bf16x8*)&Bs[(wn * 64 + j * 16 + lr) * 32 + lg * 8];
#pragma unroll
    for (int i = 0; i < 4; ++i)
#pragma unroll
      for (int j = 0; j < 4; ++j)
        acc[i][j] = __builtin_amdgcn_mfma_f32_16x16x32_bf16(af[i], bfr[j], acc[i][j], 0, 0, 0);
    __syncthreads();
  }

#pragma unroll
  for (int i = 0; i < 4; ++i) {
    const int row = bm + wm * 64 + i * 16 + lg * 4;
#pragma unroll
    for (int j = 0; j < 4; ++j) {
      const int col = bn + wn * 64 + j * 16 + lr;
      const float b = bias[col];
#pragma unroll
      for (int r = 0; r < 4; ++r)
        Cp[(size_t)(row + r) * DM + col] = acc[i][j][r] + b;
    }
  }
}

// ---------------- causal flash attention ----------------
// 4 waves / block, block owns one 32-q-row strip; keys split in 4 contiguous
// chunks (wave 3 gets the diagonal). K register-double-buffered (prefetch
// distance 1); V single-buffered, issued at tile top (hidden under softmax).
// Swapped QK^T (mfma(K,Q) -> C[k][q], lane owns one q-row), PV as
// O^T = mfma(VT, P^T). P^T redistribution via v_permlane32_swap_b32.
// lsum kept as per-lane half-row partial; row-merged once at the end.
// NOTE: plain __launch_bounds__(256) -- a (256,4) min-waves hint forced a
// 64-VGPR allocation and spilled ~50 regs to scratch (862 MB HBM, r6).

__device__ __forceinline__ void ld_k(const u16* __restrict__ kbase, bf16x8* kf) {
  kf[0] = *(const bf16x8*)&kbase[0];
  kf[1] = *(const bf16x8*)&kbase[16];
  kf[2] = *(const bf16x8*)&kbase[32];
  kf[3] = *(const bf16x8*)&kbase[48];
}
__device__ __forceinline__ void ld_v(const u16* __restrict__ vbase, bf16x8* vf) {
  vf[0] = *(const bf16x8*)&vbase[0];
  vf[1] = *(const bf16x8*)&vbase[16];
  vf[2] = *(const bf16x8*)&vbase[(size_t)32 * S_LEN];
  vf[3] = *(const bf16x8*)&vbase[(size_t)32 * S_LEN + 16];
}

template<bool DIAG>
__device__ __forceinline__ void attn_tile(const bf16x8* kf, const bf16x8* vf,
                                          const bf16x8* qf, int lld,
                                          f32x16& o0, f32x16& o1,
                                          float& m, float& lsum) {
  f32x16 s = zero16();
  __builtin_amdgcn_s_setprio(1);
  s = __builtin_amdgcn_mfma_f32_32x32x16_bf16(kf[0], qf[0], s, 0, 0, 0);
  s = __builtin_amdgcn_mfma_f32_32x32x16_bf16(kf[1], qf[1], s, 0, 0, 0);
  s = __builtin_amdgcn_mfma_f32_32x32x16_bf16(kf[2], qf[2], s, 0, 0, 0);
  s = __builtin_amdgcn_mfma_f32_32x32x16_bf16(kf[3], qf[3], s, 0, 0, 0);
  __builtin_amdgcn_s_setprio(0);

  float p[16];
#pragma unroll
  for (int r = 0; r < 16; ++r) {
    const int kl = (r & 3) + 8 * (r >> 2);   // + 4*hi folded into lld
    p[r] = (!DIAG || kl <= lld) ? s[r] : -1e30f;
  }
  // row max: in-lane tree + cross-half shuffle (full row needed for shared m)
  float t[8];
#pragma unroll
  for (int i = 0; i < 8; ++i) t[i] = fmaxf(p[i], p[i + 8]);
#pragma unroll
  for (int i = 0; i < 4; ++i) t[i] = fmaxf(t[i], t[i + 4]);
  float mx = fmaxf(fmaxf(t[0], t[1]), fmaxf(t[2], t[3]));
  mx = fmaxf(mx, __shfl_xor(mx, 32));

  if (!__all(mx <= m + THR)) {          // wave-uniform rescale (rare after warmup)
    const float mn = fmaxf(m, mx);
    const float al = exp2f(m - mn);
    m = mn;
    lsum *= al;
    o0 *= al;
    o1 *= al;
  }
#pragma unroll
  for (int r = 0; r < 16; ++r) p[r] = exp2f(p[r] - m);
  // per-lane half-row partial sum (row-merged once at the end)
  float st[8];
#pragma unroll
  for (int i = 0; i < 8; ++i) st[i] = p[i] + p[i + 8];
#pragma unroll
  for (int i = 0; i < 4; ++i) st[i] = st[i] + st[i + 4];
  lsum += (st[0] + st[1]) + (st[2] + st[3]);

  // P^T fragments: pack bf16 pairs, redistribute via permlane32_swap.
  // After pl_swap(w0,w2): lo lane w0/w2 = keys{0,1}/{4,5}; hi lane = {8,9}/{12,13}.
  u32 w0 = cvt_pk_bf16(p[0],  p[1]);
  u32 w1 = cvt_pk_bf16(p[2],  p[3]);
  u32 w2 = cvt_pk_bf16(p[4],  p[5]);
  u32 w3 = cvt_pk_bf16(p[6],  p[7]);
  u32 w4 = cvt_pk_bf16(p[8],  p[9]);
  u32 w5 = cvt_pk_bf16(p[10], p[11]);
  u32 w6 = cvt_pk_bf16(p[12], p[13]);
  u32 w7 = cvt_pk_bf16(p[14], p[15]);
  pl_swap(w0, w2);
  pl_swap(w1, w3);
  pl_swap(w4, w6);
  pl_swap(w5, w7);
  const bf16x8 pb0 = __builtin_bit_cast(bf16x8, u32x4{w0, w1, w2, w3});
  const bf16x8 pb1 = __builtin_bit_cast(bf16x8, u32x4{w4, w5, w6, w7});

  __builtin_amdgcn_s_setprio(1);
  o0 = __builtin_amdgcn_mfma_f32_32x32x16_bf16(vf[0], pb0, o0, 0, 0, 0);
  o0 = __builtin_amdgcn_mfma_f32_32x32x16_bf16(vf[1], pb1, o0, 0, 0, 0);
  o1 = __builtin_amdgcn_mfma_f32_32x32x16_bf16(vf[2], pb0, o1, 0, 0, 0);
  o1 = __builtin_amdgcn_mfma_f32_32x32x16_bf16(vf[3], pb1, o1, 0, 0, 0);
  __builtin_amdgcn_s_setprio(0);
}

// 2048 blocks x 4 waves = 8192 waves. xcd = bid&7 owns head pair {2x,2x+1};
// longest strips dispatched first within each XCD.
__global__ __launch_bounds__(256) void attn_fwd8(const u16* __restrict__ Q,
                                                 const u16* __restrict__ K,
                                                 const u16* __restrict__ VT,
                                                 u16* __restrict__ O) {
  __shared__ float ms[3][64];
  __shared__ float ls[3][64];
  __shared__ float ob[3][64][33];   // stride 33: conflict-free scalar access

  const int tid = threadIdx.x;
  const int lane = tid & 63;
  const int wv = tid >> 6;               // 0..3
  const int ll = lane & 31, hi = lane >> 5;
  const int lld = ll - 4 * hi;
  const int bid = blockIdx.x;
  const int xcd = bid & 7;
  const int i = bid >> 3;                // 0..255
  const int h = xcd * 2 + (i & 1);
  const int sIdx = 127 - (i >> 1);
  const int wqb = sIdx * 32;

  const u16* qrow = Q + (size_t)(wqb + ll) * DM + h * DH + hi * 8;
  bf16x8 qf[4];
#pragma unroll
  for (int d = 0; d < 4; ++d) qf[d] = *(const bf16x8*)&qrow[d * 16];

  const u16* Kb = K + (size_t)ll * DM + h * DH + hi * 8;
  const u16* Vb = VT + (size_t)(h * DH + ll) * S_LEN + hi * 8;

  f32x16 o0 = zero16(), o1 = zero16();
  float m = -1e30f, lsum = 0.f;

  // chunking: wave w gets cnt tiles; extras go to the HIGHEST waves so wave 3
  // always holds the diagonal tile (index ntot-1).
  const int ntot = sIdx + 1;
  const int base = ntot >> 2, rem = ntot & 3;
  const int cnt = base + ((wv >= 4 - rem) ? 1 : 0);
  const int ex = wv - (4 - rem);
  const int start = wv * base + (ex > 0 ? ex : 0);
  const int end = start + cnt;

  if (cnt > 0) {
    bf16x8 kA[4], kB[4], vf[4];
    ld_k(Kb + (size_t)(start * 32) * DM, kA);
    const int lastND = (wv == 3) ? end - 1 : end;   // wave3: final tile is DIAG
    bool cur = true;
    for (int t = start; t < lastND; ++t) {
      ld_v(Vb + t * 32, vf);
      const int nx = (t + 1 < end) ? t + 1 : t;     // prefetch next K (incl diag)
      if (cur) {
        ld_k(Kb + (size_t)(nx * 32) * DM, kB);
        attn_tile<false>(kA, vf, qf, lld, o0, o1, m, lsum);
      } else {
        ld_k(Kb + (size_t)(nx * 32) * DM, kA);
        attn_tile<false>(kB, vf, qf, lld, o0, o1, m, lsum);
      }
      cur = !cur;
    }
    if (wv == 3) {
      ld_v(Vb + (end - 1) * 32, vf);
      if (cur) attn_tile<true>(kA, vf, qf, lld, o0, o1, m, lsum);
      else     attn_tile<true>(kB, vf, qf, lld, o0, o1, m, lsum);
    }
  }

  // merge the 4 online-softmax partials (waves 1..3 -> LDS, wave 0 combines)
  if (wv > 0) {
    ms[wv - 1][lane] = m;
    ls[wv - 1][lane] = lsum;
#pragma unroll
    for (int j = 0; j < 16; ++j) ob[wv - 1][lane][j] = o0[j];
#pragma unroll
    for (int j = 0; j < 16; ++j) ob[wv - 1][lane][16 + j] = o1[j];
  }
  __syncthreads();
  if (wv == 0) {
    float M = m;
#pragma unroll
    for (int w = 0; w < 3; ++w) M = fmaxf(M, ms[w][lane]);
    const float a0 = exp2f(m - M);
    float lf = lsum * a0;
    o0 *= a0;
    o1 *= a0;
#pragma unroll
    for (int w = 0; w < 3; ++w) {
      const float aw = exp2f(ms[w][lane] - M);
      lf += ls[w][lane] * aw;
#pragma unroll
      for (int j = 0; j < 16; ++j) o0[j] += ob[w][lane][j] * aw;
#pragma unroll
      for (int j = 0; j < 16; ++j) o1[j] += ob[w][lane][16 + j] * aw;
    }
    lf += __shfl_xor(lf, 32);            // half-row partial -> full row sum
    const float inv = 1.f / lf;
    u16* orow = O + (size_t)(wqb + ll) * DM + h * DH;
#pragma unroll
    for (int g2 = 0; g2 < 4; ++g2) {
      ushort4 oa;
      oa.x = f2bf(o0[g2 * 4 + 0] * inv); oa.y = f2bf(o0[g2 * 4 + 1] * inv);
      oa.z = f2bf(o0[g2 * 4 + 2] * inv); oa.w = f2bf(o0[g2 * 4 + 3] * inv);
      *(ushort4*)&orow[g2 * 8 + hi * 4] = oa;
      ushort4 obv;
      obv.x = f2bf(o1[g2 * 4 + 0] * inv); obv.y = f2bf(o1[g2 * 4 + 1] * inv);
      obv.z = f2bf(o1[g2 * 4 + 2] * inv); obv.w = f2bf(o1[g2 * 4 + 3] * inv);
      *(ushort4*)&orow[32 + g2 * 8 + hi * 4] = obv;
    }
  }
}

// ---------------- host launch ----------------
extern "C" void kernel_launch(void* const* d_in, const int* in_sizes, int n_in,
                              void* d_out, int out_size, void* d_ws, size_t ws_size,
                              hipStream_t stream) {
  const float* x  = (const float*)d_in[0];
  const float* Wq = (const float*)d_in[1];
  const float* bq = (const float*)d_in[2];
  const float* Wk = (const float*)d_in[3];
  const float* bk = (const float*)d_in[4];
  const float* Wv = (const float*)d_in[5];
  const float* bv = (const float*)d_in[6];
  const float* Wo = (const float*)d_in[7];
  const float* bo = (const float*)d_in[8];
  float* out = (float*)d_out;

  u16* xb  = (u16*)d_ws;                      // [4096][1024]
  u16* wqb = xb  + (size_t)S_LEN * DM;        // [1024][1024] each
  u16* wkb = wqb + (size_t)DM * DM;
  u16* wvb = wkb + (size_t)DM * DM;
  u16* wob = wvb + (size_t)DM * DM;
  u16* qbf = wob + (size_t)DM * DM;           // [4096][1024] (pre-scaled by CE)
  u16* kbf = qbf + (size_t)S_LEN * DM;        // [4096][1024]
  u16* vtb = kbf + (size_t)S_LEN * DM;        // [1024][4096]  (V^T)
  u16* obf = vtb + (size_t)S_LEN * DM;        // [4096][1024]

  cvt_bf16<<<(S_LEN * DM / 4 + 255) / 256, 256, 0, stream>>>(x, xb, S_LEN * DM / 4);
  cvt_bf16_w4<<<dim3((DM * DM / 4 + 255) / 256, 4), 256, 0, stream>>>(
      Wq, Wk, Wv, Wo, wqb, wkb, wvb, wob, DM * DM / 4);

  gemm_qkv<<<dim3(S_LEN / 128, DM / 128, 3), 256, 0, stream>>>(
      xb, wqb, wkb, wvb, bq, bk, bv, qbf, kbf, vtb);

  attn_fwd8<<<dim3(2048), 256, 0, stream>>>(qbf, kbf, vtb, obf);

  gemm_out<<<dim3(S_LEN / 128, DM / 128), 256, 0, stream>>>(obf, wob, bo, out);
}

// Round 9
// 198.157 us; speedup vs baseline: 1.0291x; 1.0291x over previous
//
#include <hip/hip_runtime.h>

typedef unsigned short u16;
typedef unsigned int u32;
typedef short bf16x8 __attribute__((ext_vector_type(8)));
typedef float f32x4 __attribute__((ext_vector_type(4)));
typedef float f32x16 __attribute__((ext_vector_type(16)));
typedef u32 u32x4 __attribute__((ext_vector_type(4)));

#define S_LEN 4096
#define DM 1024
#define NH 16
#define DH 64
#define CE 0.18033688f   // (1/sqrt(64)) * log2(e)  -- folded into Q projection
#define THR 8.0f

typedef const __attribute__((address_space(1))) u32 gu32;
typedef __attribute__((address_space(3))) u32 lu32;

// raw v_exp_f32 (trans pipe, 1 op). exp2f without fast-math lowers to a ~5-op
// denormal-safe expansion on the VALU -- that was ~60% of r8's VALUBusy.
#define EXP2(x) __builtin_amdgcn_exp2f(x)

__device__ __forceinline__ u16 f2bf(float f) {
  u32 u = __builtin_bit_cast(u32, f);
  u += 0x7fff + ((u >> 16) & 1);
  return (u16)(u >> 16);
}

__device__ __forceinline__ f32x16 zero16() {
  f32x16 z;
#pragma unroll
  for (int i = 0; i < 16; ++i) z[i] = 0.f;
  return z;
}

__device__ __forceinline__ u32 cvt_pk_bf16(float lo, float hi) {
  u32 r;
  asm("v_cvt_pk_bf16_f32 %0, %1, %2" : "=v"(r) : "v"(lo), "v"(hi));
  return r;
}

// v_permlane32_swap_b32 a, b:
//   new_a[32..63] = old_b[0..31]; new_b[0..31] = old_a[32..63]; rest kept.
// SAFETY: operands must be DISTINCT SSA values (same-value operands can be
// CSE'd into one VGPR -> corrupt swap; this caused r4's NaN via swap_fmax).
__device__ __forceinline__ void pl_swap(u32& a, u32& b) {
  asm("v_permlane32_swap_b32 %0, %1" : "+v"(a), "+v"(b));
}

// ---------------- fp32 -> bf16 conversion ----------------
__global__ void cvt_bf16(const float* __restrict__ in, u16* __restrict__ out, int n4) {
  int i = blockIdx.x * blockDim.x + threadIdx.x;
  if (i < n4) {
    float4 v = ((const float4*)in)[i];
    ushort4 o;
    o.x = f2bf(v.x); o.y = f2bf(v.y); o.z = f2bf(v.z); o.w = f2bf(v.w);
    ((ushort4*)out)[i] = o;
  }
}

// fused 4-weight convert: blockIdx.y selects which weight matrix
__global__ void cvt_bf16_w4(const float* __restrict__ a, const float* __restrict__ b,
                            const float* __restrict__ c, const float* __restrict__ d,
                            u16* __restrict__ oa, u16* __restrict__ ob2,
                            u16* __restrict__ oc, u16* __restrict__ od, int n4) {
  const int w = blockIdx.y;
  const float* src = (w == 0) ? a : (w == 1) ? b : (w == 2) ? c : d;
  u16* dst = (w == 0) ? oa : (w == 1) ? ob2 : (w == 2) ? oc : od;
  int i = blockIdx.x * blockDim.x + threadIdx.x;
  if (i < n4) {
    float4 v = ((const float4*)src)[i];
    ushort4 o;
    o.x = f2bf(v.x); o.y = f2bf(v.y); o.z = f2bf(v.z); o.w = f2bf(v.w);
    ((ushort4*)dst)[i] = o;
  }
}

// ---------------- fused QKV projection GEMM ----------------
// z=0: Q = (x Wq^T + bq) * CE   -> row-major bf16
// z=1: K = x Wk^T + bk          -> row-major bf16
// z=2: V = x Wv^T + bv          -> TRANSPOSED bf16 [DM][S]
__global__ __launch_bounds__(256) void gemm_qkv(const u16* __restrict__ A,
                                                const u16* __restrict__ Wq_, const u16* __restrict__ Wk_, const u16* __restrict__ Wv_,
                                                const float* __restrict__ bq_, const float* __restrict__ bk_, const float* __restrict__ bv_,
                                                u16* __restrict__ Qo, u16* __restrict__ Ko, u16* __restrict__ Vo) {
  __shared__ __align__(16) u16 As[128 * 32];
  __shared__ __align__(16) u16 Bs[128 * 32];
  const int z = blockIdx.z;
  const u16* Bt = (z == 0) ? Wq_ : (z == 1) ? Wk_ : Wv_;
  const float* bias = (z == 0) ? bq_ : (z == 1) ? bk_ : bv_;

  const int tid = threadIdx.x;
  const int lane = tid & 63;
  const int wid = tid >> 6;
  const int wm = wid >> 1, wn = wid & 1;
  const int bm = blockIdx.x * 128, bn = blockIdx.y * 128;
  const int lr = lane & 15, lg = lane >> 4;

  f32x4 acc[4][4];
#pragma unroll
  for (int i = 0; i < 4; ++i)
#pragma unroll
    for (int j = 0; j < 4; ++j) acc[i][j] = f32x4{0.f, 0.f, 0.f, 0.f};

  const int r0 = tid >> 2;
  const int c0 = (tid & 3) * 8;
  const u16* ga0 = A + (size_t)(bm + r0) * DM + c0;
  const u16* gb0 = Bt + (size_t)(bn + r0) * DM + c0;

  for (int kt = 0; kt < DM; kt += 32) {
    __builtin_amdgcn_global_load_lds((gu32*)(ga0 + kt),            (lu32*)(As + tid * 8),        16, 0, 0);
    __builtin_amdgcn_global_load_lds((gu32*)(ga0 + 64 * DM + kt),  (lu32*)(As + 2048 + tid * 8), 16, 0, 0);
    __builtin_amdgcn_global_load_lds((gu32*)(gb0 + kt),            (lu32*)(Bs + tid * 8),        16, 0, 0);
    __builtin_amdgcn_global_load_lds((gu32*)(gb0 + 64 * DM + kt),  (lu32*)(Bs + 2048 + tid * 8), 16, 0, 0);
    __syncthreads();
    bf16x8 af[4], bfr[4];
#pragma unroll
    for (int i = 0; i < 4; ++i) af[i] = *(const bf16x8*)&As[(wm * 64 + i * 16 + lr) * 32 + lg * 8];
#pragma unroll
    for (int j = 0; j < 4; ++j) bfr[j] = *(const bf16x8*)&Bs[(wn * 64 + j * 16 + lr) * 32 + lg * 8];
#pragma unroll
    for (int i = 0; i < 4; ++i)
#pragma unroll
      for (int j = 0; j < 4; ++j)
        acc[i][j] = __builtin_amdgcn_mfma_f32_16x16x32_bf16(af[i], bfr[j], acc[i][j], 0, 0, 0);
    __syncthreads();
  }

#pragma unroll
  for (int i = 0; i < 4; ++i) {
    const int row = bm + wm * 64 + i * 16 + lg * 4;
#pragma unroll
    for (int j = 0; j < 4; ++j) {
      const int col = bn + wn * 64 + j * 16 + lr;
      const float b = bias[col];
#pragma unroll
      for (int r = 0; r < 4; ++r) {
        const float v = acc[i][j][r] + b;
        if (z == 0)      Qo[(size_t)(row + r) * DM + col] = f2bf(v * CE);
        else if (z == 1) Ko[(size_t)(row + r) * DM + col] = f2bf(v);
        else             Vo[(size_t)col * S_LEN + (row + r)] = f2bf(v);
      }
    }
  }
}

// ---------------- output GEMM: C[M,N] = A[M,K] * Bt[N,K]^T + bias (fp32 out) ----------------
__global__ __launch_bounds__(256) void gemm_out(const u16* __restrict__ A,
                                                const u16* __restrict__ Bt,
                                                const float* __restrict__ bias,
                                                float* __restrict__ Cp) {
  __shared__ __align__(16) u16 As[128 * 32];
  __shared__ __align__(16) u16 Bs[128 * 32];
  const int tid = threadIdx.x;
  const int lane = tid & 63;
  const int wid = tid >> 6;
  const int wm = wid >> 1, wn = wid & 1;
  const int bm = blockIdx.x * 128, bn = blockIdx.y * 128;
  const int lr = lane & 15, lg = lane >> 4;

  f32x4 acc[4][4];
#pragma unroll
  for (int i = 0; i < 4; ++i)
#pragma unroll
    for (int j = 0; j < 4; ++j) acc[i][j] = f32x4{0.f, 0.f, 0.f, 0.f};

  const int r0 = tid >> 2;
  const int c0 = (tid & 3) * 8;
  const u16* ga0 = A + (size_t)(bm + r0) * DM + c0;
  const u16* gb0 = Bt + (size_t)(bn + r0) * DM + c0;

  for (int kt = 0; kt < DM; kt += 32) {
    __builtin_amdgcn_global_load_lds((gu32*)(ga0 + kt),            (lu32*)(As + tid * 8),        16, 0, 0);
    __builtin_amdgcn_global_load_lds((gu32*)(ga0 + 64 * DM + kt),  (lu32*)(As + 2048 + tid * 8), 16, 0, 0);
    __builtin_amdgcn_global_load_lds((gu32*)(gb0 + kt),            (lu32*)(Bs + tid * 8),        16, 0, 0);
    __builtin_amdgcn_global_load_lds((gu32*)(gb0 + 64 * DM + kt),  (lu32*)(Bs + 2048 + tid * 8), 16, 0, 0);
    __syncthreads();
    bf16x8 af[4], bfr[4];
#pragma unroll
    for (int i = 0; i < 4; ++i) af[i] = *(const bf16x8*)&As[(wm * 64 + i * 16 + lr) * 32 + lg * 8];
#pragma unroll
    for (int j = 0; j < 4; ++j) bfr[j] = *(const bf16x8*)&Bs[(wn * 64 + j * 16 + lr) * 32 + lg * 8];
#pragma unroll
    for (int i = 0; i < 4; ++i)
#pragma unroll
      for (int j = 0; j < 4; ++j)
        acc[i][j] = __builtin_amdgcn_mfma_f32_16x16x32_bf16(af[i], bfr[j], acc[i][j], 0, 0, 0);
    __syncthreads();
  }

#pragma unroll
  for (int i = 0; i < 4; ++i) {
    const int row = bm + wm * 64 + i * 16 + lg * 4;
#pragma unroll
    for (int j = 0; j < 4; ++j) {
      const int col = bn + wn * 64 + j * 16 + lr;
      const float b = bias[col];
#pragma unroll
      for (int r = 0; r < 4; ++r)
        Cp[(size_t)(row + r) * DM + col] = acc[i][j][r] + b;
    }
  }
}

// ---------------- causal flash attention ----------------
// 4 waves / block, block owns one 32-q-row strip; keys split in 4 contiguous
// chunks (wave 3 gets the diagonal). Swapped QK^T (mfma(K,Q) -> C[k][q], lane
// owns one q-row), PV as O^T = mfma(VT, P^T). P^T redistribution via
// v_permlane32_swap_b32. lsum kept as per-lane half-row partial; row-merged
// once at the end. Two-round pairwise wave merge (17.9 KB LDS).
// NOTE: plain __launch_bounds__(256) -- a (256,4) min-waves hint forced a
// 64-VGPR allocation and spilled ~50 regs to scratch (862 MB HBM, r6).

__device__ __forceinline__ void ld_k(const u16* __restrict__ kbase, bf16x8* kf) {
  kf[0] = *(const bf16x8*)&kbase[0];
  kf[1] = *(const bf16x8*)&kbase[16];
  kf[2] = *(const bf16x8*)&kbase[32];
  kf[3] = *(const bf16x8*)&kbase[48];
}
__device__ __forceinline__ void ld_v(const u16* __restrict__ vbase, bf16x8* vf) {
  vf[0] = *(const bf16x8*)&vbase[0];
  vf[1] = *(const bf16x8*)&vbase[16];
  vf[2] = *(const bf16x8*)&vbase[(size_t)32 * S_LEN];
  vf[3] = *(const bf16x8*)&vbase[(size_t)32 * S_LEN + 16];
}

template<bool DIAG>
__device__ __forceinline__ void attn_tile(const bf16x8* kf, const bf16x8* vf,
                                          const bf16x8* qf, int lld,
                                          f32x16& o0, f32x16& o1,
                                          float& m, float& lsum) {
  f32x16 s = zero16();
  __builtin_amdgcn_s_setprio(1);
  s = __builtin_amdgcn_mfma_f32_32x32x16_bf16(kf[0], qf[0], s, 0, 0, 0);
  s = __builtin_amdgcn_mfma_f32_32x32x16_bf16(kf[1], qf[1], s, 0, 0, 0);
  s = __builtin_amdgcn_mfma_f32_32x32x16_bf16(kf[2], qf[2], s, 0, 0, 0);
  s = __builtin_amdgcn_mfma_f32_32x32x16_bf16(kf[3], qf[3], s, 0, 0, 0);
  __builtin_amdgcn_s_setprio(0);

  float p[16];
#pragma unroll
  for (int r = 0; r < 16; ++r) {
    const int kl = (r & 3) + 8 * (r >> 2);   // + 4*hi folded into lld
    p[r] = (!DIAG || kl <= lld) ? s[r] : -1e30f;
  }
  // row max: in-lane tree + cross-half shuffle (full row needed for shared m)
  float t[8];
#pragma unroll
  for (int i = 0; i < 8; ++i) t[i] = fmaxf(p[i], p[i + 8]);
#pragma unroll
  for (int i = 0; i < 4; ++i) t[i] = fmaxf(t[i], t[i + 4]);
  float mx = fmaxf(fmaxf(t[0], t[1]), fmaxf(t[2], t[3]));
  mx = fmaxf(mx, __shfl_xor(mx, 32));

  if (!__all(mx <= m + THR)) {          // wave-uniform rescale (rare after warmup)
    const float mn = fmaxf(m, mx);
    const float al = EXP2(m - mn);
    m = mn;
    lsum *= al;
    o0 *= al;
    o1 *= al;
  }
#pragma unroll
  for (int r = 0; r < 16; ++r) p[r] = EXP2(p[r] - m);
  // per-lane half-row partial sum (row-merged once at the end)
  float st[8];
#pragma unroll
  for (int i = 0; i < 8; ++i) st[i] = p[i] + p[i + 8];
#pragma unroll
  for (int i = 0; i < 4; ++i) st[i] = st[i] + st[i + 4];
  lsum += (st[0] + st[1]) + (st[2] + st[3]);

  // P^T fragments: pack bf16 pairs, redistribute via permlane32_swap.
  u32 w0 = cvt_pk_bf16(p[0],  p[1]);
  u32 w1 = cvt_pk_bf16(p[2],  p[3]);
  u32 w2 = cvt_pk_bf16(p[4],  p[5]);
  u32 w3 = cvt_pk_bf16(p[6],  p[7]);
  u32 w4 = cvt_pk_bf16(p[8],  p[9]);
  u32 w5 = cvt_pk_bf16(p[10], p[11]);
  u32 w6 = cvt_pk_bf16(p[12], p[13]);
  u32 w7 = cvt_pk_bf16(p[14], p[15]);
  pl_swap(w0, w2);
  pl_swap(w1, w3);
  pl_swap(w4, w6);
  pl_swap(w5, w7);
  const bf16x8 pb0 = __builtin_bit_cast(bf16x8, u32x4{w0, w1, w2, w3});
  const bf16x8 pb1 = __builtin_bit_cast(bf16x8, u32x4{w4, w5, w6, w7});

  __builtin_amdgcn_s_setprio(1);
  o0 = __builtin_amdgcn_mfma_f32_32x32x16_bf16(vf[0], pb0, o0, 0, 0, 0);
  o0 = __builtin_amdgcn_mfma_f32_32x32x16_bf16(vf[1], pb1, o0, 0, 0, 0);
  o1 = __builtin_amdgcn_mfma_f32_32x32x16_bf16(vf[2], pb0, o1, 0, 0, 0);
  o1 = __builtin_amdgcn_mfma_f32_32x32x16_bf16(vf[3], pb1, o1, 0, 0, 0);
  __builtin_amdgcn_s_setprio(0);
}

// 2048 blocks x 4 waves = 8192 waves. xcd = bid&7 owns head pair {2x,2x+1};
// longest strips dispatched first within each XCD.
__global__ __launch_bounds__(256) void attn_fwd9(const u16* __restrict__ Q,
                                                 const u16* __restrict__ K,
                                                 const u16* __restrict__ VT,
                                                 u16* __restrict__ O) {
  __shared__ float ms[2][64];
  __shared__ float ls[2][64];
  __shared__ float ob[2][64][33];   // stride 33: conflict-free scalar access

  const int tid = threadIdx.x;
  const int lane = tid & 63;
  const int wv = tid >> 6;               // 0..3
  const int ll = lane & 31, hi = lane >> 5;
  const int lld = ll - 4 * hi;
  const int bid = blockIdx.x;
  const int xcd = bid & 7;
  const int i = bid >> 3;                // 0..255
  const int h = xcd * 2 + (i & 1);
  const int sIdx = 127 - (i >> 1);
  const int wqb = sIdx * 32;

  const u16* qrow = Q + (size_t)(wqb + ll) * DM + h * DH + hi * 8;
  bf16x8 qf[4];
#pragma unroll
  for (int d = 0; d < 4; ++d) qf[d] = *(const bf16x8*)&qrow[d * 16];

  const u16* Kb = K + (size_t)ll * DM + h * DH + hi * 8;
  const u16* Vb = VT + (size_t)(h * DH + ll) * S_LEN + hi * 8;

  f32x16 o0 = zero16(), o1 = zero16();
  float m = -1e30f, lsum = 0.f;

  // chunking: wave w gets cnt tiles; extras go to the HIGHEST waves so wave 3
  // always holds the diagonal tile (index ntot-1).
  const int ntot = sIdx + 1;
  const int base = ntot >> 2, rem = ntot & 3;
  const int cnt = base + ((wv >= 4 - rem) ? 1 : 0);
  const int ex = wv - (4 - rem);
  const int start = wv * base + (ex > 0 ? ex : 0);
  const int end = start + cnt;

  if (cnt > 0) {
    bf16x8 kf[4], vf[4];
    const int lastND = (wv == 3) ? end - 1 : end;   // wave3: final tile is DIAG
    for (int t = start; t < lastND; ++t) {
      ld_k(Kb + (size_t)(t * 32) * DM, kf);
      ld_v(Vb + t * 32, vf);
      attn_tile<false>(kf, vf, qf, lld, o0, o1, m, lsum);
    }
    if (wv == 3) {
      ld_k(Kb + (size_t)((end - 1) * 32) * DM, kf);
      ld_v(Vb + (end - 1) * 32, vf);
      attn_tile<true>(kf, vf, qf, lld, o0, o1, m, lsum);
    }
  }

  // two-round pairwise merge: (1->0, 3->2) then (2->0). 17.9 KB LDS.
  if (wv == 1 || wv == 3) {
    const int slot = wv >> 1;
    ms[slot][lane] = m;
    ls[slot][lane] = lsum;
#pragma unroll
    for (int j = 0; j < 16; ++j) ob[slot][lane][j] = o0[j];
#pragma unroll
    for (int j = 0; j < 16; ++j) ob[slot][lane][16 + j] = o1[j];
  }
  __syncthreads();
  if (wv == 0 || wv == 2) {
    const int slot = wv >> 1;
    const float m2 = ms[slot][lane], l2 = ls[slot][lane];
    const float M = fmaxf(m, m2);
    const float a = EXP2(m - M);
    const float b = EXP2(m2 - M);
    lsum = lsum * a + l2 * b;
#pragma unroll
    for (int j = 0; j < 16; ++j) o0[j] = o0[j] * a + ob[slot][lane][j] * b;
#pragma unroll
    for (int j = 0; j < 16; ++j) o1[j] = o1[j] * a + ob[slot][lane][16 + j] * b;
    m = M;
  }
  __syncthreads();
  if (wv == 2) {
    ms[1][lane] = m;
    ls[1][lane] = lsum;
#pragma unroll
    for (int j = 0; j < 16; ++j) ob[1][lane][j] = o0[j];
#pragma unroll
    for (int j = 0; j < 16; ++j) ob[1][lane][16 + j] = o1[j];
  }
  __syncthreads();
  if (wv == 0) {
    const float m2 = ms[1][lane], l2 = ls[1][lane];
    const float M = fmaxf(m, m2);
    const float a = EXP2(m - M);
    const float b = EXP2(m2 - M);
    float lf = lsum * a + l2 * b;
#pragma unroll
    for (int j = 0; j < 16; ++j) o0[j] = o0[j] * a + ob[1][lane][j] * b;
#pragma unroll
    for (int j = 0; j < 16; ++j) o1[j] = o1[j] * a + ob[1][lane][16 + j] * b;
    lf += __shfl_xor(lf, 32);            // half-row partial -> full row sum
    const float inv = 1.f / lf;
    u16* orow = O + (size_t)(wqb + ll) * DM + h * DH;
#pragma unroll
    for (int g2 = 0; g2 < 4; ++g2) {
      ushort4 oa;
      oa.x = f2bf(o0[g2 * 4 + 0] * inv); oa.y = f2bf(o0[g2 * 4 + 1] * inv);
      oa.z = f2bf(o0[g2 * 4 + 2] * inv); oa.w = f2bf(o0[g2 * 4 + 3] * inv);
      *(ushort4*)&orow[g2 * 8 + hi * 4] = oa;
      ushort4 obv;
      obv.x = f2bf(o1[g2 * 4 + 0] * inv); obv.y = f2bf(o1[g2 * 4 + 1] * inv);
      obv.z = f2bf(o1[g2 * 4 + 2] * inv); obv.w = f2bf(o1[g2 * 4 + 3] * inv);
      *(ushort4*)&orow[32 + g2 * 8 + hi * 4] = obv;
    }
  }
}

// ---------------- host launch ----------------
extern "C" void kernel_launch(void* const* d_in, const int* in_sizes, int n_in,
                              void* d_out, int out_size, void* d_ws, size_t ws_size,
                              hipStream_t stream) {
  const float* x  = (const float*)d_in[0];
  const float* Wq = (const float*)d_in[1];
  const float* bq = (const float*)d_in[2];
  const float* Wk = (const float*)d_in[3];
  const float* bk = (const float*)d_in[4];
  const float* Wv = (const float*)d_in[5];
  const float* bv = (const float*)d_in[6];
  const float* Wo = (const float*)d_in[7];
  const float* bo = (const float*)d_in[8];
  float* out = (float*)d_out;

  u16* xb  = (u16*)d_ws;                      // [4096][1024]
  u16* wqb = xb  + (size_t)S_LEN * DM;        // [1024][1024] each
  u16* wkb = wqb + (size_t)DM * DM;
  u16* wvb = wkb + (size_t)DM * DM;
  u16* wob = wvb + (size_t)DM * DM;
  u16* qbf = wob + (size_t)DM * DM;           // [4096][1024] (pre-scaled by CE)
  u16* kbf = qbf + (size_t)S_LEN * DM;        // [4096][1024]
  u16* vtb = kbf + (size_t)S_LEN * DM;        // [1024][4096]  (V^T)
  u16* obf = vtb + (size_t)S_LEN * DM;        // [4096][1024]

  cvt_bf16<<<(S_LEN * DM / 4 + 255) / 256, 256, 0, stream>>>(x, xb, S_LEN * DM / 4);
  cvt_bf16_w4<<<dim3((DM * DM / 4 + 255) / 256, 4), 256, 0, stream>>>(
      Wq, Wk, Wv, Wo, wqb, wkb, wvb, wob, DM * DM / 4);

  gemm_qkv<<<dim3(S_LEN / 128, DM / 128, 3), 256, 0, stream>>>(
      xb, wqb, wkb, wvb, bq, bk, bv, qbf, kbf, vtb);

  attn_fwd9<<<dim3(2048), 256, 0, stream>>>(qbf, kbf, vtb, obf);

  gemm_out<<<dim3(S_LEN / 128, DM / 128), 256, 0, stream>>>(obf, wob, bo, out);
}